// Round 1
// baseline (135.214 us; speedup 1.0000x reference)
//
#include <hip/hip_runtime.h>

#define NPTS 512
#define NB 4
#define TI 16
#define TJ 32
#define PADA 68   // row stride in floats: 16B-aligned rows, (4r+k)%32 banks -> <=2-way (free)

// ---------------- Kernel 1: per-row embedding chain ----------------
// One wave (64 lanes) per row; lane t owns channel t. 4 rows per block.
__global__ __launch_bounds__(256) void rows_kernel(
    const float* __restrict__ x,
    const float* __restrict__ Wf,  const float* __restrict__ bf,
    const float* __restrict__ Wp1, const float* __restrict__ bp1,
    const float* __restrict__ Wp2, const float* __restrict__ bp2,
    const float* __restrict__ Wn,  const float* __restrict__ bn,
    const float* __restrict__ W1,  const float* __restrict__ b1,
    float* __restrict__ wsA, float* __restrict__ wsB)
{
    __shared__ float posh[4][64];
    __shared__ float projS[4][64];
    __shared__ float embS[4][64];

    const int r   = threadIdx.x >> 6;   // local row (wave)
    const int t   = threadIdx.x & 63;   // channel
    const int row = blockIdx.x * 4 + r;
    const float* xr = x + row * 16;

    // pos hidden: relu(xyz @ Wp1 + bp1)
    const float x13 = xr[13], x14 = xr[14], x15 = xr[15];
    float ph = x13 * Wp1[t] + x14 * Wp1[64 + t] + x15 * Wp1[128 + t] + bp1[t];
    ph = fmaxf(ph, 0.f);
    posh[r][t] = ph;
    __syncthreads();

    // pos = posh @ Wp2 + bp2 ; proj = feats @ Wf + bf + pos
    float acc = bp2[t];
    #pragma unroll
    for (int k = 0; k < 64; ++k) acc += posh[r][k] * Wp2[k * 64 + t];
    acc += bf[t];
    #pragma unroll
    for (int k = 0; k < 13; ++k) acc += xr[k] * Wf[k * 64 + t];
    projS[r][t] = acc;
    __syncthreads();

    // emb = proj @ Wn + bn
    float emb = bn[t];
    #pragma unroll
    for (int k = 0; k < 64; ++k) emb += projS[r][k] * Wn[k * 64 + t];
    embS[r][t] = emb;
    __syncthreads();

    // a = emb @ W1[:64] + b1  (b1 folded here);  b = emb @ W1[64:]
    float av = b1[t];
    float bv = 0.f;
    #pragma unroll
    for (int k = 0; k < 64; ++k) {
        const float e = embS[r][k];
        av += e * W1[k * 64 + t];
        bv += e * W1[(64 + k) * 64 + t];
    }
    wsA[row * 64 + t] = av;
    wsB[row * 64 + t] = bv;
}

// ---------------- Kernel 2: pairwise MLP ----------------
// Block = 16 i x 32 j tile. Thread owns pairs (i, j) and (i, j+16).
__global__ __launch_bounds__(256) void pairs_kernel(
    const float* __restrict__ wsA, const float* __restrict__ wsB,
    const float* __restrict__ W2,  const float* __restrict__ b2,
    const float* __restrict__ W3,  const float* __restrict__ b3,
    float* __restrict__ out)
{
    __shared__ float aS[TI][PADA];
    __shared__ float bS[TJ][PADA];
    __shared__ float W2s[64 * 32];
    __shared__ float b2s[32];
    __shared__ float W3s[32];

    const int tid = threadIdx.x;
    const int bidx = blockIdx.x;
    const int jt = bidx & 15;          // 16 j-tiles
    const int it = (bidx >> 4) & 31;   // 32 i-tiles
    const int bb = bidx >> 9;          // batch
    const int i0 = it * TI, j0 = jt * TJ;

    const float* aG = wsA + (bb * NPTS + i0) * 64;
    const float* bG = wsB + (bb * NPTS + j0) * 64;

    // stage a-tile: 1024 floats (1 float4/thread)
    {
        const int r = tid >> 4, c = (tid & 15) * 4;
        const float4 v = *(const float4*)(aG + r * 64 + c);
        aS[r][c] = v.x; aS[r][c + 1] = v.y; aS[r][c + 2] = v.z; aS[r][c + 3] = v.w;
    }
    // stage b-tile: 2048 floats (2 float4/thread)
    #pragma unroll
    for (int p = 0; p < 2; ++p) {
        const int idx = tid + p * 256;
        const int r = idx >> 4, c = (idx & 15) * 4;
        const float4 v = *(const float4*)(bG + r * 64 + c);
        bS[r][c] = v.x; bS[r][c + 1] = v.y; bS[r][c + 2] = v.z; bS[r][c + 3] = v.w;
    }
    // stage W2 (contiguous, no pad needed: reads are wave-uniform broadcasts)
    {
        const float4* src = (const float4*)W2;
        float4* dst = (float4*)W2s;
        dst[tid] = src[tid];
        dst[tid + 256] = src[tid + 256];
    }
    if (tid < 32) { b2s[tid] = b2[tid]; W3s[tid] = W3[tid]; }
    __syncthreads();

    const int i_loc = tid >> 4;    // 0..15
    const int j_loc = tid & 15;    // 0..15 ; pairs (i_loc,j_loc) & (i_loc,j_loc+16)

    float acc0[32], acc1[32];
    #pragma unroll
    for (int m = 0; m < 32; ++m) { acc0[m] = 0.f; acc1[m] = 0.f; }

    #pragma unroll 4
    for (int k = 0; k < 64; ++k) {
        const float a_ik = aS[i_loc][k];
        const float h0 = fmaxf(a_ik + bS[j_loc][k], 0.f);
        const float h1 = fmaxf(a_ik + bS[j_loc + 16][k], 0.f);
        const float4* wrow = (const float4*)(W2s + k * 32);
        #pragma unroll
        for (int m4 = 0; m4 < 8; ++m4) {
            const float4 w = wrow[m4];
            acc0[m4 * 4 + 0] += h0 * w.x; acc0[m4 * 4 + 1] += h0 * w.y;
            acc0[m4 * 4 + 2] += h0 * w.z; acc0[m4 * 4 + 3] += h0 * w.w;
            acc1[m4 * 4 + 0] += h1 * w.x; acc1[m4 * 4 + 1] += h1 * w.y;
            acc1[m4 * 4 + 2] += h1 * w.z; acc1[m4 * 4 + 3] += h1 * w.w;
        }
    }

    const float bias3 = b3[0];
    float l0 = bias3, l1 = bias3;
    #pragma unroll
    for (int m = 0; m < 32; ++m) {
        l0 += fmaxf(acc0[m] + b2s[m], 0.f) * W3s[m];
        l1 += fmaxf(acc1[m] + b2s[m], 0.f) * W3s[m];
    }

    float* orow = out + (size_t)(bb * NPTS + i0 + i_loc) * NPTS + j0;
    orow[j_loc] = l0;        // 16 consecutive dwords per 16-lane group: coalesced
    orow[j_loc + 16] = l1;
}

extern "C" void kernel_launch(void* const* d_in, const int* in_sizes, int n_in,
                              void* d_out, int out_size, void* d_ws, size_t ws_size,
                              hipStream_t stream) {
    const float* x   = (const float*)d_in[0];
    const float* Wf  = (const float*)d_in[1];
    const float* bf  = (const float*)d_in[2];
    const float* Wp1 = (const float*)d_in[3];
    const float* bp1 = (const float*)d_in[4];
    const float* Wp2 = (const float*)d_in[5];
    const float* bp2 = (const float*)d_in[6];
    const float* Wn  = (const float*)d_in[7];
    const float* bn  = (const float*)d_in[8];
    const float* W1  = (const float*)d_in[9];
    const float* b1  = (const float*)d_in[10];
    const float* W2  = (const float*)d_in[11];
    const float* b2  = (const float*)d_in[12];
    const float* W3  = (const float*)d_in[13];
    const float* b3  = (const float*)d_in[14];

    float* wsA = (float*)d_ws;                 // 2048*64 floats
    float* wsB = wsA + NB * NPTS * 64;         // 2048*64 floats (ws needs 1 MiB)

    rows_kernel<<<NB * NPTS / 4, 256, 0, stream>>>(
        x, Wf, bf, Wp1, bp1, Wp2, bp2, Wn, bn, W1, b1, wsA, wsB);

    pairs_kernel<<<NB * (NPTS / TI) * (NPTS / TJ), 256, 0, stream>>>(
        wsA, wsB, W2, b2, W3, b3, (float*)d_out);
}

// Round 2
// 131.537 us; speedup vs baseline: 1.0279x; 1.0279x over previous
//
#include <hip/hip_runtime.h>

#define NPTS 512
#define NB 4
#define TI 32
#define TJ 32
#define PADA 68   // row stride floats: 16B-aligned rows; (4j+k)%32 -> worst 2-way (free, m136)

// ---------------- Kernel 1: per-row embedding chain ----------------
// One wave (64 lanes) per row; lane t owns channel t. 4 rows per block.
__global__ __launch_bounds__(256) void rows_kernel(
    const float* __restrict__ x,
    const float* __restrict__ Wf,  const float* __restrict__ bf,
    const float* __restrict__ Wp1, const float* __restrict__ bp1,
    const float* __restrict__ Wp2, const float* __restrict__ bp2,
    const float* __restrict__ Wn,  const float* __restrict__ bn,
    const float* __restrict__ W1,  const float* __restrict__ b1,
    float* __restrict__ wsA, float* __restrict__ wsB)
{
    __shared__ float posh[4][64];
    __shared__ float projS[4][64];
    __shared__ float embS[4][64];

    const int r   = threadIdx.x >> 6;   // local row (wave)
    const int t   = threadIdx.x & 63;   // channel
    const int row = blockIdx.x * 4 + r;
    const float* xr = x + row * 16;

    // pos hidden: relu(xyz @ Wp1 + bp1)
    const float x13 = xr[13], x14 = xr[14], x15 = xr[15];
    float ph = x13 * Wp1[t] + x14 * Wp1[64 + t] + x15 * Wp1[128 + t] + bp1[t];
    ph = fmaxf(ph, 0.f);
    posh[r][t] = ph;
    __syncthreads();

    // pos = posh @ Wp2 + bp2 ; proj = feats @ Wf + bf + pos
    float acc = bp2[t];
    #pragma unroll
    for (int k = 0; k < 64; ++k) acc += posh[r][k] * Wp2[k * 64 + t];
    acc += bf[t];
    #pragma unroll
    for (int k = 0; k < 13; ++k) acc += xr[k] * Wf[k * 64 + t];
    projS[r][t] = acc;
    __syncthreads();

    // emb = proj @ Wn + bn
    float emb = bn[t];
    #pragma unroll
    for (int k = 0; k < 64; ++k) emb += projS[r][k] * Wn[k * 64 + t];
    embS[r][t] = emb;
    __syncthreads();

    // a = emb @ W1[:64] + b1  (b1 folded here);  b = emb @ W1[64:]
    float av = b1[t];
    float bv = 0.f;
    #pragma unroll
    for (int k = 0; k < 64; ++k) {
        const float e = embS[r][k];
        av += e * W1[k * 64 + t];
        bv += e * W1[(64 + k) * 64 + t];
    }
    wsA[row * 64 + t] = av;
    wsB[row * 64 + t] = bv;
}

// ---------------- Kernel 2: pairwise MLP ----------------
// Block = 32 i x 32 j tile, 256 threads, 4 pairs/thread:
// (i_loc, i_loc+16) x (j_loc, j_loc+16).
// W2/b2/W3/b3 read via wave-uniform addresses -> SMEM (s_load) path, no LDS.
__global__ __launch_bounds__(256) void pairs_kernel(
    const float* __restrict__ wsA, const float* __restrict__ wsB,
    const float* __restrict__ W2,  const float* __restrict__ b2,
    const float* __restrict__ W3,  const float* __restrict__ b3,
    float* __restrict__ out)
{
    __shared__ float aS[TI][PADA];
    __shared__ float bS[TJ][PADA];

    const int tid  = threadIdx.x;
    const int bidx = blockIdx.x;
    const int jt = bidx & 15;          // 16 j-tiles
    const int it = (bidx >> 4) & 15;   // 16 i-tiles
    const int bb = bidx >> 8;          // batch
    const int i0 = it * TI, j0 = jt * TJ;

    const float* aG = wsA + (bb * NPTS + i0) * 64;
    const float* bG = wsB + (bb * NPTS + j0) * 64;

    // stage a-tile and b-tile: 2048 floats each = 2 float4/thread each
    #pragma unroll
    for (int p = 0; p < 2; ++p) {
        const int idx = tid + p * 256;
        const int r = idx >> 4, c = (idx & 15) * 4;
        const float4 va = *(const float4*)(aG + r * 64 + c);
        aS[r][c] = va.x; aS[r][c + 1] = va.y; aS[r][c + 2] = va.z; aS[r][c + 3] = va.w;
        const float4 vb = *(const float4*)(bG + r * 64 + c);
        bS[r][c] = vb.x; bS[r][c + 1] = vb.y; bS[r][c + 2] = vb.z; bS[r][c + 3] = vb.w;
    }
    __syncthreads();

    const int i_loc = tid >> 4;    // 0..15 -> rows i_loc, i_loc+16
    const int j_loc = tid & 15;    // 0..15 -> cols j_loc, j_loc+16

    float acc00[32], acc01[32], acc10[32], acc11[32];
    #pragma unroll
    for (int m = 0; m < 32; ++m) { acc00[m] = 0.f; acc01[m] = 0.f; acc10[m] = 0.f; acc11[m] = 0.f; }

    const float4* __restrict__ W2v = (const float4*)W2;

    #pragma unroll 2
    for (int k = 0; k < 64; ++k) {
        const float a0 = aS[i_loc][k];
        const float a1 = aS[i_loc + 16][k];
        const float b0v = bS[j_loc][k];
        const float b1v = bS[j_loc + 16][k];
        const float h00 = fmaxf(a0 + b0v, 0.f);
        const float h01 = fmaxf(a0 + b1v, 0.f);
        const float h10 = fmaxf(a1 + b0v, 0.f);
        const float h11 = fmaxf(a1 + b1v, 0.f);
        #pragma unroll
        for (int m4 = 0; m4 < 8; ++m4) {
            const float4 w = W2v[k * 8 + m4];   // wave-uniform -> s_load
            acc00[m4 * 4 + 0] += h00 * w.x; acc00[m4 * 4 + 1] += h00 * w.y;
            acc00[m4 * 4 + 2] += h00 * w.z; acc00[m4 * 4 + 3] += h00 * w.w;
            acc01[m4 * 4 + 0] += h01 * w.x; acc01[m4 * 4 + 1] += h01 * w.y;
            acc01[m4 * 4 + 2] += h01 * w.z; acc01[m4 * 4 + 3] += h01 * w.w;
            acc10[m4 * 4 + 0] += h10 * w.x; acc10[m4 * 4 + 1] += h10 * w.y;
            acc10[m4 * 4 + 2] += h10 * w.z; acc10[m4 * 4 + 3] += h10 * w.w;
            acc11[m4 * 4 + 0] += h11 * w.x; acc11[m4 * 4 + 1] += h11 * w.y;
            acc11[m4 * 4 + 2] += h11 * w.z; acc11[m4 * 4 + 3] += h11 * w.w;
        }
    }

    const float bias3 = b3[0];
    float l00 = bias3, l01 = bias3, l10 = bias3, l11 = bias3;
    #pragma unroll
    for (int m = 0; m < 32; ++m) {
        const float b2m = b2[m];   // uniform -> SGPR
        const float w3m = W3[m];   // uniform -> SGPR
        l00 += fmaxf(acc00[m] + b2m, 0.f) * w3m;
        l01 += fmaxf(acc01[m] + b2m, 0.f) * w3m;
        l10 += fmaxf(acc10[m] + b2m, 0.f) * w3m;
        l11 += fmaxf(acc11[m] + b2m, 0.f) * w3m;
    }

    float* orow0 = out + (size_t)(bb * NPTS + i0 + i_loc) * NPTS + j0;
    float* orow1 = out + (size_t)(bb * NPTS + i0 + i_loc + 16) * NPTS + j0;
    orow0[j_loc]      = l00;   // 16 consecutive dwords per 16-lane group: coalesced
    orow0[j_loc + 16] = l01;
    orow1[j_loc]      = l10;
    orow1[j_loc + 16] = l11;
}

extern "C" void kernel_launch(void* const* d_in, const int* in_sizes, int n_in,
                              void* d_out, int out_size, void* d_ws, size_t ws_size,
                              hipStream_t stream) {
    const float* x   = (const float*)d_in[0];
    const float* Wf  = (const float*)d_in[1];
    const float* bf  = (const float*)d_in[2];
    const float* Wp1 = (const float*)d_in[3];
    const float* bp1 = (const float*)d_in[4];
    const float* Wp2 = (const float*)d_in[5];
    const float* bp2 = (const float*)d_in[6];
    const float* Wn  = (const float*)d_in[7];
    const float* bn  = (const float*)d_in[8];
    const float* W1  = (const float*)d_in[9];
    const float* b1  = (const float*)d_in[10];
    const float* W2  = (const float*)d_in[11];
    const float* b2  = (const float*)d_in[12];
    const float* W3  = (const float*)d_in[13];
    const float* b3  = (const float*)d_in[14];

    float* wsA = (float*)d_ws;                 // 2048*64 floats
    float* wsB = wsA + NB * NPTS * 64;         // 2048*64 floats (ws needs 1 MiB)

    rows_kernel<<<NB * NPTS / 4, 256, 0, stream>>>(
        x, Wf, bf, Wp1, bp1, Wp2, bp2, Wn, bn, W1, b1, wsA, wsB);

    pairs_kernel<<<NB * (NPTS / TI) * (NPTS / TJ), 256, 0, stream>>>(
        wsA, wsB, W2, b2, W3, b3, (float*)d_out);
}

// Round 3
// 108.616 us; speedup vs baseline: 1.2449x; 1.2110x over previous
//
#include <hip/hip_runtime.h>
#include <stdint.h>

#define NPTS 512
#define NB 4
#define TJB 128    // j columns per block
#define PADB 68    // bS row stride (floats): 272 B = 16B-aligned, worst 2-way bank alias (free)

typedef __attribute__((ext_vector_type(4))) float floatx4;
typedef __attribute__((ext_vector_type(8))) short short8;

union S8U { uint32_t u[4]; short8 s; };
union FU  { float f; uint32_t u; };

__device__ __forceinline__ uint32_t fbits(float f){ FU x; x.f = f; return x.u; }
__device__ __forceinline__ float bitsf(uint32_t u){ FU x; x.u = u; return x.f; }

// Truncation split of two fp32 into packed-bf16 hi dword + lo dword.
// hi = top16(f) (exact remainder goes to lo); lo = top16(f - hi_as_f32).
// Dropped error ~2^-16 relative; products hi*hi+hi*lo+lo*hi recover fp32-class accuracy.
__device__ __forceinline__ void split2(float f0, float f1, uint32_t& hp, uint32_t& lp){
    const uint32_t u0 = fbits(f0), u1 = fbits(f1);
    hp = __builtin_amdgcn_perm(u1, u0, 0x07060302u);        // {u1.hi16, u0.hi16}
    const float l0 = f0 - bitsf(u0 & 0xFFFF0000u);
    const float l1 = f1 - bitsf(u1 & 0xFFFF0000u);
    lp = __builtin_amdgcn_perm(fbits(l1), fbits(l0), 0x07060302u);
}

// ---------------- Kernel 1: per-row embedding chain ----------------
// One wave per row; lane t owns channel t. 4-way split accumulators break the
// 64-deep dependent FMA chain (256 cyc -> ~70 cyc per stage).
__global__ __launch_bounds__(256) void rows_kernel(
    const float* __restrict__ x,
    const float* __restrict__ Wf,  const float* __restrict__ bf,
    const float* __restrict__ Wp1, const float* __restrict__ bp1,
    const float* __restrict__ Wp2, const float* __restrict__ bp2,
    const float* __restrict__ Wn,  const float* __restrict__ bn,
    const float* __restrict__ W1,  const float* __restrict__ b1,
    float* __restrict__ wsA, float* __restrict__ wsB)
{
    __shared__ float posh[4][64];
    __shared__ float projS[4][64];
    __shared__ float embS[4][64];

    const int r   = threadIdx.x >> 6;
    const int t   = threadIdx.x & 63;
    const int row = blockIdx.x * 4 + r;
    const float* xr = x + row * 16;

    const float x13 = xr[13], x14 = xr[14], x15 = xr[15];
    float ph = x13 * Wp1[t] + x14 * Wp1[64 + t] + x15 * Wp1[128 + t] + bp1[t];
    posh[r][t] = fmaxf(ph, 0.f);
    __syncthreads();

    float s0 = 0.f, s1 = 0.f, s2 = 0.f, s3 = 0.f;
    #pragma unroll
    for (int k = 0; k < 64; k += 4) {
        s0 += posh[r][k    ] * Wp2[(k    ) * 64 + t];
        s1 += posh[r][k + 1] * Wp2[(k + 1) * 64 + t];
        s2 += posh[r][k + 2] * Wp2[(k + 2) * 64 + t];
        s3 += posh[r][k + 3] * Wp2[(k + 3) * 64 + t];
    }
    float acc = bp2[t] + ((s0 + s1) + (s2 + s3)) + bf[t];
    float f0 = 0.f, f1 = 0.f, f2 = 0.f, f3 = 0.f;
    #pragma unroll
    for (int k = 0; k < 12; k += 4) {
        f0 += xr[k    ] * Wf[(k    ) * 64 + t];
        f1 += xr[k + 1] * Wf[(k + 1) * 64 + t];
        f2 += xr[k + 2] * Wf[(k + 2) * 64 + t];
        f3 += xr[k + 3] * Wf[(k + 3) * 64 + t];
    }
    acc += ((f0 + f1) + (f2 + f3)) + xr[12] * Wf[12 * 64 + t];
    projS[r][t] = acc;
    __syncthreads();

    float e0 = 0.f, e1 = 0.f, e2 = 0.f, e3 = 0.f;
    #pragma unroll
    for (int k = 0; k < 64; k += 4) {
        e0 += projS[r][k    ] * Wn[(k    ) * 64 + t];
        e1 += projS[r][k + 1] * Wn[(k + 1) * 64 + t];
        e2 += projS[r][k + 2] * Wn[(k + 2) * 64 + t];
        e3 += projS[r][k + 3] * Wn[(k + 3) * 64 + t];
    }
    embS[r][t] = bn[t] + ((e0 + e1) + (e2 + e3));
    __syncthreads();

    float a0 = 0.f, a1 = 0.f, a2 = 0.f, a3 = 0.f;
    float v0 = 0.f, v1 = 0.f, v2 = 0.f, v3 = 0.f;
    #pragma unroll
    for (int k = 0; k < 64; k += 4) {
        const float g0 = embS[r][k], g1 = embS[r][k + 1], g2 = embS[r][k + 2], g3 = embS[r][k + 3];
        a0 += g0 * W1[(k    ) * 64 + t];
        a1 += g1 * W1[(k + 1) * 64 + t];
        a2 += g2 * W1[(k + 2) * 64 + t];
        a3 += g3 * W1[(k + 3) * 64 + t];
        v0 += g0 * W1[(64 + k    ) * 64 + t];
        v1 += g1 * W1[(64 + k + 1) * 64 + t];
        v2 += g2 * W1[(64 + k + 2) * 64 + t];
        v3 += g3 * W1[(64 + k + 3) * 64 + t];
    }
    wsA[row * 64 + t] = b1[t] + ((a0 + a1) + (a2 + a3));   // b1 folded into a
    wsB[row * 64 + t] = (v0 + v1) + (v2 + v3);
}

// ---------------- Kernel 2: pairwise MLP via split-bf16 MFMA ----------------
// GEMM view: D[j,m] = H[j,k] @ W2[k,m] per i, H built on the fly in A-layout.
// Block: 4 i (one per wave) x 128 j. Wave processes 8 M-tiles of 16 j's.
__global__ __launch_bounds__(256) void pairs_kernel(
    const float* __restrict__ wsA, const float* __restrict__ wsB,
    const float* __restrict__ W2,  const float* __restrict__ b2,
    const float* __restrict__ W3,  const float* __restrict__ b3,
    float* __restrict__ out)
{
    __shared__ float bS[TJB][PADB];

    const int tid = threadIdx.x;
    const int w   = tid >> 6;        // wave -> i offset
    const int l   = tid & 63;
    const int q   = l >> 4;          // quad
    const int c   = l & 15;          // n / m-col lane index
    const int q8  = q * 8;

    const int bidx = blockIdx.x;
    const int jt = bidx & 3;             // 4 j-tiles of 128
    const int ib = (bidx >> 2) & 127;    // 128 i-groups of 4
    const int bb = bidx >> 9;            // batch
    const int j0 = jt * TJB;
    const int i  = ib * 4 + w;

    // stage b-tile: 128 rows x 64 floats
    const float* bG = wsB + (bb * NPTS + j0) * 64;
    #pragma unroll
    for (int p = 0; p < 8; ++p) {
        const int flat = p * 256 + tid;
        const int rr = flat >> 4, c4 = (flat & 15) * 4;
        *(float4*)&bS[rr][c4] = *(const float4*)(bG + rr * 64 + c4);
    }

    // W2 fragments in B-operand layout: lane holds W2[k=kt*32+q8+e][nt*16+c]
    short8 Whi[2][2], Wlo[2][2];
    #pragma unroll
    for (int kt = 0; kt < 2; ++kt)
        #pragma unroll
        for (int nt = 0; nt < 2; ++nt) {
            S8U hu, lu;
            #pragma unroll
            for (int d = 0; d < 4; ++d) {
                const float g0 = W2[(kt * 32 + q8 + 2 * d    ) * 32 + nt * 16 + c];
                const float g1 = W2[(kt * 32 + q8 + 2 * d + 1) * 32 + nt * 16 + c];
                split2(g0, g1, hu.u[d], lu.u[d]);
            }
            Whi[kt][nt] = hu.s; Wlo[kt][nt] = lu.s;
        }

    const float b2c = b2[c], b2c16 = b2[c + 16];
    const float w3c = W3[c], w3c16 = W3[c + 16];
    const float b3v = b3[0];

    // hoisted a-row (b1 already folded): k = q8..q8+7, 32+q8..32+q8+7
    const float* aG = wsA + (bb * NPTS + i) * 64;
    float a[16];
    #pragma unroll
    for (int e = 0; e < 8; ++e) { a[e] = aG[q8 + e]; a[8 + e] = aG[32 + q8 + e]; }

    __syncthreads();

    float* orow = out + ((size_t)(bb * NPTS + i)) * NPTS + j0;

    #pragma unroll 1
    for (int mt = 0; mt < 8; ++mt) {
        const int m = mt * 16 + c;      // j-local row this lane builds for A
        float bh[16];
        *(float4*)&bh[0]  = *(const float4*)&bS[m][q8];
        *(float4*)&bh[4]  = *(const float4*)&bS[m][q8 + 4];
        *(float4*)&bh[8]  = *(const float4*)&bS[m][32 + q8];
        *(float4*)&bh[12] = *(const float4*)&bS[m][32 + q8 + 4];

        float h[16];
        #pragma unroll
        for (int e = 0; e < 16; ++e) h[e] = fmaxf(a[e] + bh[e], 0.f);

        S8U h0h, h0l, h1h, h1l;
        #pragma unroll
        for (int d = 0; d < 4; ++d) {
            split2(h[2 * d],     h[2 * d + 1],     h0h.u[d], h0l.u[d]);
            split2(h[8 + 2 * d], h[8 + 2 * d + 1], h1h.u[d], h1l.u[d]);
        }

        floatx4 acc0 = {0.f, 0.f, 0.f, 0.f};
        floatx4 acc1 = {0.f, 0.f, 0.f, 0.f};
        acc0 = __builtin_amdgcn_mfma_f32_16x16x32_bf16(h0h.s, Whi[0][0], acc0, 0, 0, 0);
        acc0 = __builtin_amdgcn_mfma_f32_16x16x32_bf16(h0l.s, Whi[0][0], acc0, 0, 0, 0);
        acc0 = __builtin_amdgcn_mfma_f32_16x16x32_bf16(h0h.s, Wlo[0][0], acc0, 0, 0, 0);
        acc0 = __builtin_amdgcn_mfma_f32_16x16x32_bf16(h1h.s, Whi[1][0], acc0, 0, 0, 0);
        acc0 = __builtin_amdgcn_mfma_f32_16x16x32_bf16(h1l.s, Whi[1][0], acc0, 0, 0, 0);
        acc0 = __builtin_amdgcn_mfma_f32_16x16x32_bf16(h1h.s, Wlo[1][0], acc0, 0, 0, 0);
        acc1 = __builtin_amdgcn_mfma_f32_16x16x32_bf16(h0h.s, Whi[0][1], acc1, 0, 0, 0);
        acc1 = __builtin_amdgcn_mfma_f32_16x16x32_bf16(h0l.s, Whi[0][1], acc1, 0, 0, 0);
        acc1 = __builtin_amdgcn_mfma_f32_16x16x32_bf16(h0h.s, Wlo[0][1], acc1, 0, 0, 0);
        acc1 = __builtin_amdgcn_mfma_f32_16x16x32_bf16(h1h.s, Whi[1][1], acc1, 0, 0, 0);
        acc1 = __builtin_amdgcn_mfma_f32_16x16x32_bf16(h1l.s, Whi[1][1], acc1, 0, 0, 0);
        acc1 = __builtin_amdgcn_mfma_f32_16x16x32_bf16(h1h.s, Wlo[1][1], acc1, 0, 0, 0);

        // layer 3: per C/D row r (j = mt*16 + q*4 + r), reduce over m via butterfly
        float res[4];
        #pragma unroll
        for (int r = 0; r < 4; ++r) {
            float v = fmaxf(acc0[r] + b2c, 0.f) * w3c + fmaxf(acc1[r] + b2c16, 0.f) * w3c16;
            v += __shfl_xor(v, 1, 64);
            v += __shfl_xor(v, 2, 64);
            v += __shfl_xor(v, 4, 64);
            v += __shfl_xor(v, 8, 64);
            res[r] = v;
        }
        const float outv = (c == 0) ? res[0] : ((c == 1) ? res[1] : ((c == 2) ? res[2] : res[3]));
        if (c < 4) orow[mt * 16 + q * 4 + c] = outv + b3v;
    }
}

extern "C" void kernel_launch(void* const* d_in, const int* in_sizes, int n_in,
                              void* d_out, int out_size, void* d_ws, size_t ws_size,
                              hipStream_t stream) {
    const float* x   = (const float*)d_in[0];
    const float* Wf  = (const float*)d_in[1];
    const float* bf  = (const float*)d_in[2];
    const float* Wp1 = (const float*)d_in[3];
    const float* bp1 = (const float*)d_in[4];
    const float* Wp2 = (const float*)d_in[5];
    const float* bp2 = (const float*)d_in[6];
    const float* Wn  = (const float*)d_in[7];
    const float* bn  = (const float*)d_in[8];
    const float* W1  = (const float*)d_in[9];
    const float* b1  = (const float*)d_in[10];
    const float* W2  = (const float*)d_in[11];
    const float* b2  = (const float*)d_in[12];
    const float* W3  = (const float*)d_in[13];
    const float* b3  = (const float*)d_in[14];

    float* wsA = (float*)d_ws;                 // 2048*64 floats
    float* wsB = wsA + NB * NPTS * 64;         // 2048*64 floats (ws needs 1 MiB)

    rows_kernel<<<NB * NPTS / 4, 256, 0, stream>>>(
        x, Wf, bf, Wp1, bp1, Wp2, bp2, Wn, bn, W1, b1, wsA, wsB);

    pairs_kernel<<<NB * NPTS / 4 * 4, 256, 0, stream>>>(
        wsA, wsB, W2, b2, W3, b3, (float*)d_out);
}

// Round 5
// 101.216 us; speedup vs baseline: 1.3359x; 1.0731x over previous
//
#include <hip/hip_runtime.h>
#include <stdint.h>

#define NPTS 512
#define NB 4
#define TJB 128
#define PADB 68    // bS row stride (floats): 16B-aligned rows, <=2-way bank alias (free)
#define SOST 40    // sO row stride (halfs): 80 B -> 16B-aligned half8 reads, <=2-way writes

typedef __attribute__((ext_vector_type(4))) float floatx4;
typedef __fp16 fp16x2 __attribute__((ext_vector_type(2)));      // matches cvt_pkrtz return type
typedef _Float16 half2v __attribute__((ext_vector_type(2)));
typedef _Float16 half8v __attribute__((ext_vector_type(8)));

union H8 { fp16x2 p2[4]; half2v h2[4]; half8v h8; };

// ---------------- Kernel 1: per-row embedding chain ----------------
__global__ __launch_bounds__(256) void rows_kernel(
    const float* __restrict__ x,
    const float* __restrict__ Wf,  const float* __restrict__ bf,
    const float* __restrict__ Wp1, const float* __restrict__ bp1,
    const float* __restrict__ Wp2, const float* __restrict__ bp2,
    const float* __restrict__ Wn,  const float* __restrict__ bn,
    const float* __restrict__ W1,  const float* __restrict__ b1,
    float* __restrict__ wsA, float* __restrict__ wsB)
{
    __shared__ float posh[4][64];
    __shared__ float projS[4][64];
    __shared__ float embS[4][64];

    const int r   = threadIdx.x >> 6;
    const int t   = threadIdx.x & 63;
    const int row = blockIdx.x * 4 + r;
    const float* xr = x + row * 16;

    const float x13 = xr[13], x14 = xr[14], x15 = xr[15];
    float ph = x13 * Wp1[t] + x14 * Wp1[64 + t] + x15 * Wp1[128 + t] + bp1[t];
    posh[r][t] = fmaxf(ph, 0.f);
    __syncthreads();

    float s0 = 0.f, s1 = 0.f, s2 = 0.f, s3 = 0.f;
    #pragma unroll
    for (int k = 0; k < 64; k += 4) {
        s0 += posh[r][k    ] * Wp2[(k    ) * 64 + t];
        s1 += posh[r][k + 1] * Wp2[(k + 1) * 64 + t];
        s2 += posh[r][k + 2] * Wp2[(k + 2) * 64 + t];
        s3 += posh[r][k + 3] * Wp2[(k + 3) * 64 + t];
    }
    float acc = bp2[t] + ((s0 + s1) + (s2 + s3)) + bf[t];
    float f0 = 0.f, f1 = 0.f, f2 = 0.f, f3 = 0.f;
    #pragma unroll
    for (int k = 0; k < 12; k += 4) {
        f0 += xr[k    ] * Wf[(k    ) * 64 + t];
        f1 += xr[k + 1] * Wf[(k + 1) * 64 + t];
        f2 += xr[k + 2] * Wf[(k + 2) * 64 + t];
        f3 += xr[k + 3] * Wf[(k + 3) * 64 + t];
    }
    acc += ((f0 + f1) + (f2 + f3)) + xr[12] * Wf[12 * 64 + t];
    projS[r][t] = acc;
    __syncthreads();

    float e0 = 0.f, e1 = 0.f, e2 = 0.f, e3 = 0.f;
    #pragma unroll
    for (int k = 0; k < 64; k += 4) {
        e0 += projS[r][k    ] * Wn[(k    ) * 64 + t];
        e1 += projS[r][k + 1] * Wn[(k + 1) * 64 + t];
        e2 += projS[r][k + 2] * Wn[(k + 2) * 64 + t];
        e3 += projS[r][k + 3] * Wn[(k + 3) * 64 + t];
    }
    embS[r][t] = bn[t] + ((e0 + e1) + (e2 + e3));
    __syncthreads();

    float a0 = 0.f, a1 = 0.f, a2 = 0.f, a3 = 0.f;
    float v0 = 0.f, v1 = 0.f, v2 = 0.f, v3 = 0.f;
    #pragma unroll
    for (int k = 0; k < 64; k += 4) {
        const float g0 = embS[r][k], g1 = embS[r][k + 1], g2 = embS[r][k + 2], g3 = embS[r][k + 3];
        a0 += g0 * W1[(k    ) * 64 + t];
        a1 += g1 * W1[(k + 1) * 64 + t];
        a2 += g2 * W1[(k + 2) * 64 + t];
        a3 += g3 * W1[(k + 3) * 64 + t];
        v0 += g0 * W1[(64 + k    ) * 64 + t];
        v1 += g1 * W1[(64 + k + 1) * 64 + t];
        v2 += g2 * W1[(64 + k + 2) * 64 + t];
        v3 += g3 * W1[(64 + k + 3) * 64 + t];
    }
    wsA[row * 64 + t] = b1[t] + ((a0 + a1) + (a2 + a3));   // b1 folded into a
    wsB[row * 64 + t] = (v0 + v1) + (v2 + v3);
}

// ---------------- Kernel 2: pairwise MLP, single-term f16 MFMA ----------------
// Block: 4 i (one per wave) x 128 j. Per mt (16 j):
//   H = relu(a+b) -> pkrtz f16 -> 4 MFMA vs W2-f16 (B-layout)
//   epilogue: relu(S+b2) -> pkrtz sigma-interleaved -> LDS round trip ->
//             1 MFMA vs sigma-permuted W3 (replaces 16 serial shuffles)
__global__ __launch_bounds__(256) void pairs_kernel(
    const float* __restrict__ wsA, const float* __restrict__ wsB,
    const float* __restrict__ W2,  const float* __restrict__ b2,
    const float* __restrict__ W3,  const float* __restrict__ b3,
    float* __restrict__ out)
{
    __shared__ float bS[TJB][PADB];
    __shared__ _Float16 sO[4][16][SOST];   // wave-private 16j x 32m f16 (sigma order)

    const int tid = threadIdx.x;
    const int w   = tid >> 6;        // wave -> i offset
    const int l   = tid & 63;
    const int q   = l >> 4;          // quad
    const int c   = l & 15;
    const int q8  = q * 8;

    const int bidx = blockIdx.x;
    const int jt = bidx & 3;             // 4 j-tiles of 128
    const int ib = (bidx >> 2) & 127;    // 128 i-groups of 4
    const int bb = bidx >> 9;            // batch
    const int j0 = jt * TJB;
    const int i  = ib * 4 + w;

    // stage b-tile: 128 rows x 64 floats
    const float* bG = wsB + (bb * NPTS + j0) * 64;
    #pragma unroll
    for (int p = 0; p < 8; ++p) {
        const int flat = p * 256 + tid;
        const int rr = flat >> 4, c4 = (flat & 15) * 4;
        *(float4*)&bS[rr][c4] = *(const float4*)(bG + rr * 64 + c4);
    }

    // W2 f16 fragments, B-layout: lane holds W2[k=kt*32+q8+e][nt*16+c], RNE
    half8v Wf16[2][2];
    #pragma unroll
    for (int kt = 0; kt < 2; ++kt)
        #pragma unroll
        for (int nt = 0; nt < 2; ++nt) {
            H8 u;
            #pragma unroll
            for (int d = 0; d < 4; ++d) {
                half2v t;
                t[0] = (_Float16)W2[(kt * 32 + q8 + 2 * d    ) * 32 + nt * 16 + c];
                t[1] = (_Float16)W2[(kt * 32 + q8 + 2 * d + 1) * 32 + nt * 16 + c];
                u.h2[d] = t;
            }
            Wf16[kt][nt] = u.h8;
        }

    // W3 sigma-permuted B-frag (broadcast across c): pos p holds W3[(p>>1)+16*(p&1)]
    half8v w3f;
    #pragma unroll
    for (int e = 0; e < 8; ++e) {
        const int p = q8 + e;
        w3f[e] = (_Float16)W3[(p >> 1) + ((p & 1) << 4)];
    }

    const float b2c = b2[c], b2c16 = b2[c + 16];
    const float b3v = b3[0];

    // hoisted a-row (b1 folded): k = q8..q8+7, 32+q8..32+q8+7
    const float* aG = wsA + (bb * NPTS + i) * 64;
    float a[16];
    #pragma unroll
    for (int e = 0; e < 8; ++e) { a[e] = aG[q8 + e]; a[8 + e] = aG[32 + q8 + e]; }

    __syncthreads();

    float* orow = out + ((size_t)(bb * NPTS + i)) * NPTS + j0;

    #pragma unroll 2
    for (int mt = 0; mt < 8; ++mt) {
        const int m = mt * 16 + c;      // j-local row this lane builds for A
        float bh[16];
        *(float4*)&bh[0]  = *(const float4*)&bS[m][q8];
        *(float4*)&bh[4]  = *(const float4*)&bS[m][q8 + 4];
        *(float4*)&bh[8]  = *(const float4*)&bS[m][32 + q8];
        *(float4*)&bh[12] = *(const float4*)&bS[m][32 + q8 + 4];

        float h[16];
        #pragma unroll
        for (int e = 0; e < 16; ++e) h[e] = fmaxf(a[e] + bh[e], 0.f);

        H8 h0, h1;
        #pragma unroll
        for (int d = 0; d < 4; ++d) {
            h0.p2[d] = __builtin_amdgcn_cvt_pkrtz(h[2 * d],     h[2 * d + 1]);
            h1.p2[d] = __builtin_amdgcn_cvt_pkrtz(h[8 + 2 * d], h[8 + 2 * d + 1]);
        }

        floatx4 acc0 = {0.f, 0.f, 0.f, 0.f};
        floatx4 acc1 = {0.f, 0.f, 0.f, 0.f};
        acc0 = __builtin_amdgcn_mfma_f32_16x16x32_f16(h0.h8, Wf16[0][0], acc0, 0, 0, 0);
        acc0 = __builtin_amdgcn_mfma_f32_16x16x32_f16(h1.h8, Wf16[1][0], acc0, 0, 0, 0);
        acc1 = __builtin_amdgcn_mfma_f32_16x16x32_f16(h0.h8, Wf16[0][1], acc1, 0, 0, 0);
        acc1 = __builtin_amdgcn_mfma_f32_16x16x32_f16(h1.h8, Wf16[1][1], acc1, 0, 0, 0);

        // epilogue: R = relu(S + b2) packed (m=c, m=c+16) -> sigma position 2c
        #pragma unroll
        for (int r = 0; r < 4; ++r) {
            const float r0 = fmaxf(acc0[r] + b2c,   0.f);
            const float r1 = fmaxf(acc1[r] + b2c16, 0.f);
            *(fp16x2*)&sO[w][q * 4 + r][2 * c] = __builtin_amdgcn_cvt_pkrtz(r0, r1);
        }
        // A-layout read: lane holds R[j=c][sigma(q8..q8+7)] (16B-aligned half8)
        const half8v ar = *(const half8v*)&sO[w][c][q8];

        floatx4 dl = {0.f, 0.f, 0.f, 0.f};
        dl = __builtin_amdgcn_mfma_f32_16x16x32_f16(ar, w3f, dl, 0, 0, 0);

        // D rows = j = q*4+reg, identical across cols; lane c<4 takes reg c
        const float lg = (c == 0) ? dl[0] : ((c == 1) ? dl[1] : ((c == 2) ? dl[2] : dl[3]));
        if (c < 4) orow[mt * 16 + q * 4 + c] = lg + b3v;
    }
}

extern "C" void kernel_launch(void* const* d_in, const int* in_sizes, int n_in,
                              void* d_out, int out_size, void* d_ws, size_t ws_size,
                              hipStream_t stream) {
    const float* x   = (const float*)d_in[0];
    const float* Wf  = (const float*)d_in[1];
    const float* bf  = (const float*)d_in[2];
    const float* Wp1 = (const float*)d_in[3];
    const float* bp1 = (const float*)d_in[4];
    const float* Wp2 = (const float*)d_in[5];
    const float* bp2 = (const float*)d_in[6];
    const float* Wn  = (const float*)d_in[7];
    const float* bn  = (const float*)d_in[8];
    const float* W1  = (const float*)d_in[9];
    const float* b1  = (const float*)d_in[10];
    const float* W2  = (const float*)d_in[11];
    const float* b2  = (const float*)d_in[12];
    const float* W3  = (const float*)d_in[13];
    const float* b3  = (const float*)d_in[14];

    float* wsA = (float*)d_ws;                 // 2048*64 floats
    float* wsB = wsA + NB * NPTS * 64;         // 2048*64 floats (ws needs 1 MiB)

    rows_kernel<<<NB * NPTS / 4, 256, 0, stream>>>(
        x, Wf, bf, Wp1, bp1, Wp2, bp2, Wn, bn, W1, b1, wsA, wsB);

    pairs_kernel<<<NB * 128 * 4, 256, 0, stream>>>(
        wsA, wsB, W2, b2, W3, b3, (float*)d_out);
}

// Round 6
// 99.366 us; speedup vs baseline: 1.3608x; 1.0186x over previous
//
#include <hip/hip_runtime.h>
#include <stdint.h>

#define NPTS 512
#define NB 4
#define TJB 128
#define BST 72     // bS row stride (halfs): 144 B = 16B-aligned; b128 patterns hit min 8 lanes/bank
#define SOST 40    // sO row stride (halfs): 80 B, 16B-aligned half8 reads, 2-way writes (free)

typedef __attribute__((ext_vector_type(4))) float floatx4;
typedef __fp16 fp16x2 __attribute__((ext_vector_type(2)));      // cvt_pkrtz return type
typedef _Float16 half2v __attribute__((ext_vector_type(2)));
typedef _Float16 half8v __attribute__((ext_vector_type(8)));

union H8 { fp16x2 p2[4]; half2v h2[4]; half8v h8; };

// ---------------- Kernel 1: per-row embedding chain ----------------
// One wave per row; lane t owns channel t. Outputs a/b rows quantized to f16
// (RNE, 2^-11 rel) so pairs_kernel can run packed-f16 math end-to-end.
__global__ __launch_bounds__(256) void rows_kernel(
    const float* __restrict__ x,
    const float* __restrict__ Wf,  const float* __restrict__ bf,
    const float* __restrict__ Wp1, const float* __restrict__ bp1,
    const float* __restrict__ Wp2, const float* __restrict__ bp2,
    const float* __restrict__ Wn,  const float* __restrict__ bn,
    const float* __restrict__ W1,  const float* __restrict__ b1,
    _Float16* __restrict__ wsA, _Float16* __restrict__ wsB)
{
    __shared__ float posh[4][64];
    __shared__ float projS[4][64];
    __shared__ float embS[4][64];

    const int r   = threadIdx.x >> 6;
    const int t   = threadIdx.x & 63;
    const int row = blockIdx.x * 4 + r;
    const float* xr = x + row * 16;

    const float x13 = xr[13], x14 = xr[14], x15 = xr[15];
    float ph = x13 * Wp1[t] + x14 * Wp1[64 + t] + x15 * Wp1[128 + t] + bp1[t];
    posh[r][t] = fmaxf(ph, 0.f);
    __syncthreads();

    float s0 = 0.f, s1 = 0.f, s2 = 0.f, s3 = 0.f;
    #pragma unroll
    for (int k = 0; k < 64; k += 4) {
        s0 += posh[r][k    ] * Wp2[(k    ) * 64 + t];
        s1 += posh[r][k + 1] * Wp2[(k + 1) * 64 + t];
        s2 += posh[r][k + 2] * Wp2[(k + 2) * 64 + t];
        s3 += posh[r][k + 3] * Wp2[(k + 3) * 64 + t];
    }
    float acc = bp2[t] + ((s0 + s1) + (s2 + s3)) + bf[t];
    float f0 = 0.f, f1 = 0.f, f2 = 0.f, f3 = 0.f;
    #pragma unroll
    for (int k = 0; k < 12; k += 4) {
        f0 += xr[k    ] * Wf[(k    ) * 64 + t];
        f1 += xr[k + 1] * Wf[(k + 1) * 64 + t];
        f2 += xr[k + 2] * Wf[(k + 2) * 64 + t];
        f3 += xr[k + 3] * Wf[(k + 3) * 64 + t];
    }
    acc += ((f0 + f1) + (f2 + f3)) + xr[12] * Wf[12 * 64 + t];
    projS[r][t] = acc;
    __syncthreads();

    float e0 = 0.f, e1 = 0.f, e2 = 0.f, e3 = 0.f;
    #pragma unroll
    for (int k = 0; k < 64; k += 4) {
        e0 += projS[r][k    ] * Wn[(k    ) * 64 + t];
        e1 += projS[r][k + 1] * Wn[(k + 1) * 64 + t];
        e2 += projS[r][k + 2] * Wn[(k + 2) * 64 + t];
        e3 += projS[r][k + 3] * Wn[(k + 3) * 64 + t];
    }
    embS[r][t] = bn[t] + ((e0 + e1) + (e2 + e3));
    __syncthreads();

    float a0 = 0.f, a1 = 0.f, a2 = 0.f, a3 = 0.f;
    float v0 = 0.f, v1 = 0.f, v2 = 0.f, v3 = 0.f;
    #pragma unroll
    for (int k = 0; k < 64; k += 4) {
        const float g0 = embS[r][k], g1 = embS[r][k + 1], g2 = embS[r][k + 2], g3 = embS[r][k + 3];
        a0 += g0 * W1[(k    ) * 64 + t];
        a1 += g1 * W1[(k + 1) * 64 + t];
        a2 += g2 * W1[(k + 2) * 64 + t];
        a3 += g3 * W1[(k + 3) * 64 + t];
        v0 += g0 * W1[(64 + k    ) * 64 + t];
        v1 += g1 * W1[(64 + k + 1) * 64 + t];
        v2 += g2 * W1[(64 + k + 2) * 64 + t];
        v3 += g3 * W1[(64 + k + 3) * 64 + t];
    }
    wsA[row * 64 + t] = (_Float16)(b1[t] + ((a0 + a1) + (a2 + a3)));  // b1 folded
    wsB[row * 64 + t] = (_Float16)((v0 + v1) + (v2 + v3));
}

// ---------------- Kernel 2: pairwise MLP, packed-f16 MFMA ----------------
// Block: 4 i (one per wave) x 128 j. Per mt (16 j):
//   H = pk_max(pk_add(a,b),0) -> 4 MFMA vs W2-f16 (b2 pre-loaded into C)
//   epilogue: pkrtz(S) -> pk_max -> LDS round trip -> 1 MFMA vs sigma-permuted W3
__global__ __launch_bounds__(256) void pairs_kernel(
    const _Float16* __restrict__ wsA, const _Float16* __restrict__ wsB,
    const float* __restrict__ W2,  const float* __restrict__ b2,
    const float* __restrict__ W3,  const float* __restrict__ b3,
    float* __restrict__ out)
{
    __shared__ _Float16 bS[TJB][BST];
    __shared__ _Float16 sO[4][16][SOST];   // wave-private 16j x 32m f16 (sigma order)

    const int tid = threadIdx.x;
    const int w   = tid >> 6;        // wave -> i offset
    const int l   = tid & 63;
    const int q   = l >> 4;          // quad
    const int c   = l & 15;
    const int q8  = q * 8;

    const int bidx = blockIdx.x;
    const int jt = bidx & 3;             // 4 j-tiles of 128
    const int ib = (bidx >> 2) & 127;    // 128 i-groups of 4
    const int bb = bidx >> 9;            // batch
    const int j0 = jt * TJB;
    const int i  = ib * 4 + w;

    // stage b-tile: 128 rows x 64 halfs = 16 KB, half8 per 16B chunk
    const _Float16* bG = wsB + (bb * NPTS + j0) * 64;
    #pragma unroll
    for (int p = 0; p < 4; ++p) {
        const int flat = p * 256 + tid;
        const int rr = flat >> 3, ch = (flat & 7) * 8;
        *(half8v*)&bS[rr][ch] = *(const half8v*)(bG + rr * 64 + ch);
    }

    // W2 f16 fragments, B-layout: lane holds W2[k=kt*32+q8+e][nt*16+c], RNE
    half8v Wf16[2][2];
    #pragma unroll
    for (int kt = 0; kt < 2; ++kt)
        #pragma unroll
        for (int nt = 0; nt < 2; ++nt) {
            H8 u;
            #pragma unroll
            for (int e = 0; e < 8; ++e)
                u.h8[e] = (_Float16)W2[(kt * 32 + q8 + e) * 32 + nt * 16 + c];
            Wf16[kt][nt] = u.h8;
        }

    // W3 sigma-permuted B-frag: pos p holds W3[(p>>1)+16*(p&1)]
    half8v w3f;
    #pragma unroll
    for (int e = 0; e < 8; ++e) {
        const int p = q8 + e;
        w3f[e] = (_Float16)W3[(p >> 1) + ((p & 1) << 4)];
    }

    const float b2c = b2[c], b2c16 = b2[c + 16];
    const float b3v = b3[0];

    // hoisted a-row (b1 folded), f16: k = q8..q8+7, 32+q8..32+q8+7
    const _Float16* aG = wsA + (bb * NPTS + i) * 64;
    const half8v a0v = *(const half8v*)(aG + q8);
    const half8v a1v = *(const half8v*)(aG + 32 + q8);
    const half8v zero8 = (half8v)(_Float16)0.0f;

    __syncthreads();

    float* orow = out + ((size_t)(bb * NPTS + i)) * NPTS + j0;

    #pragma unroll 4
    for (int mt = 0; mt < 8; ++mt) {
        const int m = mt * 16 + c;      // j-local row this lane builds for A
        const half8v b0v = *(const half8v*)&bS[m][q8];
        const half8v b1v = *(const half8v*)&bS[m][32 + q8];

        // H = relu(a + b) in packed f16 (v_pk_add_f16 + v_pk_max_f16)
        const half8v h0 = __builtin_elementwise_max(a0v + b0v, zero8);
        const half8v h1 = __builtin_elementwise_max(a1v + b1v, zero8);

        // b2 folded into C operand (D = A*B + C exact)
        floatx4 acc0 = {b2c, b2c, b2c, b2c};
        floatx4 acc1 = {b2c16, b2c16, b2c16, b2c16};
        acc0 = __builtin_amdgcn_mfma_f32_16x16x32_f16(h0, Wf16[0][0], acc0, 0, 0, 0);
        acc0 = __builtin_amdgcn_mfma_f32_16x16x32_f16(h1, Wf16[1][0], acc0, 0, 0, 0);
        acc1 = __builtin_amdgcn_mfma_f32_16x16x32_f16(h0, Wf16[0][1], acc1, 0, 0, 0);
        acc1 = __builtin_amdgcn_mfma_f32_16x16x32_f16(h1, Wf16[1][1], acc1, 0, 0, 0);

        // epilogue: R = relu(S) packed (m=c, m=c+16) -> sigma position 2c
        #pragma unroll
        for (int r = 0; r < 4; ++r) {
            H8 pk;
            pk.p2[0] = __builtin_amdgcn_cvt_pkrtz(acc0[r], acc1[r]);
            pk.h2[0] = __builtin_elementwise_max(pk.h2[0], (half2v)(_Float16)0.0f);
            *(half2v*)&sO[w][q * 4 + r][2 * c] = pk.h2[0];
        }
        // A-layout read: lane holds R[j=c][sigma(q8..q8+7)] (16B-aligned half8)
        const half8v ar = *(const half8v*)&sO[w][c][q8];

        floatx4 dl = {0.f, 0.f, 0.f, 0.f};
        dl = __builtin_amdgcn_mfma_f32_16x16x32_f16(ar, w3f, dl, 0, 0, 0);

        // D rows = j = q*4+reg, identical across cols; lane c<4 takes reg c
        const float lg = (c == 0) ? dl[0] : ((c == 1) ? dl[1] : ((c == 2) ? dl[2] : dl[3]));
        if (c < 4) orow[mt * 16 + q * 4 + c] = lg + b3v;
    }
}

extern "C" void kernel_launch(void* const* d_in, const int* in_sizes, int n_in,
                              void* d_out, int out_size, void* d_ws, size_t ws_size,
                              hipStream_t stream) {
    const float* x   = (const float*)d_in[0];
    const float* Wf  = (const float*)d_in[1];
    const float* bf  = (const float*)d_in[2];
    const float* Wp1 = (const float*)d_in[3];
    const float* bp1 = (const float*)d_in[4];
    const float* Wp2 = (const float*)d_in[5];
    const float* bp2 = (const float*)d_in[6];
    const float* Wn  = (const float*)d_in[7];
    const float* bn  = (const float*)d_in[8];
    const float* W1  = (const float*)d_in[9];
    const float* b1  = (const float*)d_in[10];
    const float* W2  = (const float*)d_in[11];
    const float* b2  = (const float*)d_in[12];
    const float* W3  = (const float*)d_in[13];
    const float* b3  = (const float*)d_in[14];

    _Float16* wsA = (_Float16*)d_ws;           // 2048*64 halfs (256 KB)
    _Float16* wsB = wsA + NB * NPTS * 64;      // 2048*64 halfs

    rows_kernel<<<NB * NPTS / 4, 256, 0, stream>>>(
        x, Wf, bf, Wp1, bp1, Wp2, bp2, Wn, bn, W1, b1, wsA, wsB);

    pairs_kernel<<<NB * 128 * 4, 256, 0, stream>>>(
        wsA, wsB, W2, b2, W3, b3, (float*)d_out);
}

// Round 7
// 96.765 us; speedup vs baseline: 1.3973x; 1.0269x over previous
//
#include <hip/hip_runtime.h>
#include <stdint.h>

#define NPTS 512
#define NB 4
#define TJB 128
#define BST 72     // bS row stride (halfs): 144 B, 16B-aligned; b128 read patterns <=2-way
#define SOST 40    // sO row stride (halfs): 80 B, 16B-aligned half8 reads, <=2-way writes

typedef __attribute__((ext_vector_type(4))) float floatx4;
typedef __fp16 fp16x2 __attribute__((ext_vector_type(2)));      // cvt_pkrtz return type
typedef _Float16 half2v __attribute__((ext_vector_type(2)));
typedef _Float16 half8v __attribute__((ext_vector_type(8)));

union H8 { fp16x2 p2[4]; half2v h2[4]; half8v h8; };

// ---------------- Kernel 1: per-row embedding chain ----------------
__global__ __launch_bounds__(256) void rows_kernel(
    const float* __restrict__ x,
    const float* __restrict__ Wf,  const float* __restrict__ bf,
    const float* __restrict__ Wp1, const float* __restrict__ bp1,
    const float* __restrict__ Wp2, const float* __restrict__ bp2,
    const float* __restrict__ Wn,  const float* __restrict__ bn,
    const float* __restrict__ W1,  const float* __restrict__ b1,
    _Float16* __restrict__ wsA, _Float16* __restrict__ wsB)
{
    __shared__ float posh[4][64];
    __shared__ float projS[4][64];
    __shared__ float embS[4][64];

    const int r   = threadIdx.x >> 6;
    const int t   = threadIdx.x & 63;
    const int row = blockIdx.x * 4 + r;
    const float* xr = x + row * 16;

    const float x13 = xr[13], x14 = xr[14], x15 = xr[15];
    float ph = x13 * Wp1[t] + x14 * Wp1[64 + t] + x15 * Wp1[128 + t] + bp1[t];
    posh[r][t] = fmaxf(ph, 0.f);
    __syncthreads();

    float s0 = 0.f, s1 = 0.f, s2 = 0.f, s3 = 0.f;
    #pragma unroll
    for (int k = 0; k < 64; k += 4) {
        s0 += posh[r][k    ] * Wp2[(k    ) * 64 + t];
        s1 += posh[r][k + 1] * Wp2[(k + 1) * 64 + t];
        s2 += posh[r][k + 2] * Wp2[(k + 2) * 64 + t];
        s3 += posh[r][k + 3] * Wp2[(k + 3) * 64 + t];
    }
    float acc = bp2[t] + ((s0 + s1) + (s2 + s3)) + bf[t];
    float f0 = 0.f, f1 = 0.f, f2 = 0.f, f3 = 0.f;
    #pragma unroll
    for (int k = 0; k < 12; k += 4) {
        f0 += xr[k    ] * Wf[(k    ) * 64 + t];
        f1 += xr[k + 1] * Wf[(k + 1) * 64 + t];
        f2 += xr[k + 2] * Wf[(k + 2) * 64 + t];
        f3 += xr[k + 3] * Wf[(k + 3) * 64 + t];
    }
    acc += ((f0 + f1) + (f2 + f3)) + xr[12] * Wf[12 * 64 + t];
    projS[r][t] = acc;
    __syncthreads();

    float e0 = 0.f, e1 = 0.f, e2 = 0.f, e3 = 0.f;
    #pragma unroll
    for (int k = 0; k < 64; k += 4) {
        e0 += projS[r][k    ] * Wn[(k    ) * 64 + t];
        e1 += projS[r][k + 1] * Wn[(k + 1) * 64 + t];
        e2 += projS[r][k + 2] * Wn[(k + 2) * 64 + t];
        e3 += projS[r][k + 3] * Wn[(k + 3) * 64 + t];
    }
    embS[r][t] = bn[t] + ((e0 + e1) + (e2 + e3));
    __syncthreads();

    float a0 = 0.f, a1 = 0.f, a2 = 0.f, a3 = 0.f;
    float v0 = 0.f, v1 = 0.f, v2 = 0.f, v3 = 0.f;
    #pragma unroll
    for (int k = 0; k < 64; k += 4) {
        const float g0 = embS[r][k], g1 = embS[r][k + 1], g2 = embS[r][k + 2], g3 = embS[r][k + 3];
        a0 += g0 * W1[(k    ) * 64 + t];
        a1 += g1 * W1[(k + 1) * 64 + t];
        a2 += g2 * W1[(k + 2) * 64 + t];
        a3 += g3 * W1[(k + 3) * 64 + t];
        v0 += g0 * W1[(64 + k    ) * 64 + t];
        v1 += g1 * W1[(64 + k + 1) * 64 + t];
        v2 += g2 * W1[(64 + k + 2) * 64 + t];
        v3 += g3 * W1[(64 + k + 3) * 64 + t];
    }
    wsA[row * 64 + t] = (_Float16)(b1[t] + ((a0 + a1) + (a2 + a3)));  // b1 folded
    wsB[row * 64 + t] = (_Float16)((v0 + v1) + (v2 + v3));
}

// ---------------- Kernel 2: pairwise MLP, packed-f16 MFMA, 2 i/wave ----------------
// Block: 4 waves x 2 i = 8 i x 128 j. Per mt (16 j): shared b-row reads feed both
// i-chains; 8 main MFMA + 2 epilogue MFMA; independent chains give ILP across the
// epilogue's LDS round-trip.
__global__ __launch_bounds__(256) void pairs_kernel(
    const _Float16* __restrict__ wsA, const _Float16* __restrict__ wsB,
    const float* __restrict__ W2,  const float* __restrict__ b2,
    const float* __restrict__ W3,  const float* __restrict__ b3,
    float* __restrict__ out)
{
    __shared__ _Float16 bS[TJB][BST];
    __shared__ _Float16 sO[4][2][16][SOST];   // [wave][i-slot][j][sigma-m]

    const int tid = threadIdx.x;
    const int w   = tid >> 6;
    const int l   = tid & 63;
    const int q   = l >> 4;
    const int c   = l & 15;
    const int q8  = q * 8;

    const int bidx = blockIdx.x;
    const int jt = bidx & 3;             // 4 j-tiles of 128
    const int ig = (bidx >> 2) & 63;     // 64 i-groups of 8
    const int bb = bidx >> 8;            // batch
    const int j0 = jt * TJB;
    const int i0 = ig * 8 + w * 2;       // wave handles i0, i0+1

    // stage b-tile: 128 rows x 64 halfs = 16 KB
    const _Float16* bG = wsB + (bb * NPTS + j0) * 64;
    #pragma unroll
    for (int p = 0; p < 4; ++p) {
        const int flat = p * 256 + tid;
        const int rr = flat >> 3, ch = (flat & 7) * 8;
        *(half8v*)&bS[rr][ch] = *(const half8v*)(bG + rr * 64 + ch);
    }

    // W2 f16 fragments, B-layout: lane holds W2[k=kt*32+q8+e][nt*16+c]
    half8v Wf16[2][2];
    #pragma unroll
    for (int kt = 0; kt < 2; ++kt)
        #pragma unroll
        for (int nt = 0; nt < 2; ++nt) {
            H8 u;
            #pragma unroll
            for (int e = 0; e < 8; ++e)
                u.h8[e] = (_Float16)W2[(kt * 32 + q8 + e) * 32 + nt * 16 + c];
            Wf16[kt][nt] = u.h8;
        }

    // W3 sigma-permuted B-frag: pos p holds W3[(p>>1)+16*(p&1)]
    half8v w3f;
    #pragma unroll
    for (int e = 0; e < 8; ++e) {
        const int p = q8 + e;
        w3f[e] = (_Float16)W3[(p >> 1) + ((p & 1) << 4)];
    }

    const float b2c = b2[c], b2c16 = b2[c + 16];
    const float b3v = b3[0];

    // a-rows for both i (b1 folded), f16
    const _Float16* aG0 = wsA + (bb * NPTS + i0) * 64;
    const _Float16* aG1 = aG0 + 64;
    const half8v aA0 = *(const half8v*)(aG0 + q8);
    const half8v aA1 = *(const half8v*)(aG0 + 32 + q8);
    const half8v aB0 = *(const half8v*)(aG1 + q8);
    const half8v aB1 = *(const half8v*)(aG1 + 32 + q8);
    const half8v zero8 = (half8v)(_Float16)0.0f;

    __syncthreads();

    float* orow0 = out + ((size_t)(bb * NPTS + i0)) * NPTS + j0;
    float* orow1 = orow0 + NPTS;

    #pragma unroll 2
    for (int mt = 0; mt < 8; ++mt) {
        const int m = mt * 16 + c;
        const half8v b0v = *(const half8v*)&bS[m][q8];
        const half8v b1v = *(const half8v*)&bS[m][32 + q8];

        // H = relu(a + b), packed f16; b-rows shared across both i
        const half8v hA0 = __builtin_elementwise_max(aA0 + b0v, zero8);
        const half8v hA1 = __builtin_elementwise_max(aA1 + b1v, zero8);
        const half8v hB0 = __builtin_elementwise_max(aB0 + b0v, zero8);
        const half8v hB1 = __builtin_elementwise_max(aB1 + b1v, zero8);

        floatx4 aA0c = {b2c, b2c, b2c, b2c};
        floatx4 aA1c = {b2c16, b2c16, b2c16, b2c16};
        floatx4 aB0c = aA0c, aB1c = aA1c;
        aA0c = __builtin_amdgcn_mfma_f32_16x16x32_f16(hA0, Wf16[0][0], aA0c, 0, 0, 0);
        aA0c = __builtin_amdgcn_mfma_f32_16x16x32_f16(hA1, Wf16[1][0], aA0c, 0, 0, 0);
        aA1c = __builtin_amdgcn_mfma_f32_16x16x32_f16(hA0, Wf16[0][1], aA1c, 0, 0, 0);
        aA1c = __builtin_amdgcn_mfma_f32_16x16x32_f16(hA1, Wf16[1][1], aA1c, 0, 0, 0);
        aB0c = __builtin_amdgcn_mfma_f32_16x16x32_f16(hB0, Wf16[0][0], aB0c, 0, 0, 0);
        aB0c = __builtin_amdgcn_mfma_f32_16x16x32_f16(hB1, Wf16[1][0], aB0c, 0, 0, 0);
        aB1c = __builtin_amdgcn_mfma_f32_16x16x32_f16(hB0, Wf16[0][1], aB1c, 0, 0, 0);
        aB1c = __builtin_amdgcn_mfma_f32_16x16x32_f16(hB1, Wf16[1][1], aB1c, 0, 0, 0);

        // epilogue, both i: R = relu(S) -> sigma position 2c -> LDS -> MFMA vs W3
        #pragma unroll
        for (int r = 0; r < 4; ++r) {
            H8 pkA, pkB;
            pkA.p2[0] = __builtin_amdgcn_cvt_pkrtz(aA0c[r], aA1c[r]);
            pkA.h2[0] = __builtin_elementwise_max(pkA.h2[0], (half2v)(_Float16)0.0f);
            *(half2v*)&sO[w][0][q * 4 + r][2 * c] = pkA.h2[0];
            pkB.p2[0] = __builtin_amdgcn_cvt_pkrtz(aB0c[r], aB1c[r]);
            pkB.h2[0] = __builtin_elementwise_max(pkB.h2[0], (half2v)(_Float16)0.0f);
            *(half2v*)&sO[w][1][q * 4 + r][2 * c] = pkB.h2[0];
        }
        const half8v arA = *(const half8v*)&sO[w][0][c][q8];
        const half8v arB = *(const half8v*)&sO[w][1][c][q8];

        floatx4 dlA = {b3v, b3v, b3v, b3v};
        floatx4 dlB = {b3v, b3v, b3v, b3v};
        dlA = __builtin_amdgcn_mfma_f32_16x16x32_f16(arA, w3f, dlA, 0, 0, 0);
        dlB = __builtin_amdgcn_mfma_f32_16x16x32_f16(arB, w3f, dlB, 0, 0, 0);

        const float lgA = (c == 0) ? dlA[0] : ((c == 1) ? dlA[1] : ((c == 2) ? dlA[2] : dlA[3]));
        const float lgB = (c == 0) ? dlB[0] : ((c == 1) ? dlB[1] : ((c == 2) ? dlB[2] : dlB[3]));
        if (c < 4) {
            orow0[mt * 16 + q * 4 + c] = lgA;
            orow1[mt * 16 + q * 4 + c] = lgB;
        }
    }
}

extern "C" void kernel_launch(void* const* d_in, const int* in_sizes, int n_in,
                              void* d_out, int out_size, void* d_ws, size_t ws_size,
                              hipStream_t stream) {
    const float* x   = (const float*)d_in[0];
    const float* Wf  = (const float*)d_in[1];
    const float* bf  = (const float*)d_in[2];
    const float* Wp1 = (const float*)d_in[3];
    const float* bp1 = (const float*)d_in[4];
    const float* Wp2 = (const float*)d_in[5];
    const float* bp2 = (const float*)d_in[6];
    const float* Wn  = (const float*)d_in[7];
    const float* bn  = (const float*)d_in[8];
    const float* W1  = (const float*)d_in[9];
    const float* b1  = (const float*)d_in[10];
    const float* W2  = (const float*)d_in[11];
    const float* b2  = (const float*)d_in[12];
    const float* W3  = (const float*)d_in[13];
    const float* b3  = (const float*)d_in[14];

    _Float16* wsA = (_Float16*)d_ws;           // 2048*64 halfs (256 KB)
    _Float16* wsB = wsA + NB * NPTS * 64;      // 2048*64 halfs

    rows_kernel<<<NB * NPTS / 4, 256, 0, stream>>>(
        x, Wf, bf, Wp1, bp1, Wp2, bp2, Wn, bn, W1, b1, wsA, wsB);

    pairs_kernel<<<NB * 64 * 4, 256, 0, stream>>>(
        wsA, wsB, W2, b2, W3, b3, (float*)d_out);
}